// Round 4
// baseline (383.445 us; speedup 1.0000x reference)
//
#include <hip/hip_runtime.h>
#include <math.h>

#define NUM_EXPERTS 16
#define HIDDEN 1024
#define INTER 768
#define TOKENS 64
#define TOPK 2
#define NPAIRS (TOKENS*TOPK)   // 128
#define GRP 8                  // tokens staged per group
#define NZ 2                   // token-group slices in grid.z

__device__ __forceinline__ float dot4(float4 a, float4 b) {
    return a.x*b.x + a.y*b.y + a.z*b.z + a.w*b.w;
}

// Deterministic expert pair-list build: wave 0 ballots over pairs [0,64) and
// [64,128). List is sorted by pair index -> identical across all blocks.
__device__ inline void build_plist(const int* __restrict__ topk_ids, int e,
                                   int tid, int* s_plist, int* s_np) {
    if (tid < 64) {
        const int lane = tid;
        int m0 = (topk_ids[lane]      == e);
        int m1 = (topk_ids[lane + 64] == e);
        unsigned long long b0 = __ballot(m0);
        unsigned long long b1 = __ballot(m1);
        int n0 = __popcll(b0);
        unsigned long long below = (lane == 0) ? 0ull : ((1ull << lane) - 1ull);
        if (m0) s_plist[__popcll(b0 & below)]      = lane;
        if (m1) s_plist[n0 + __popcll(b1 & below)] = lane + 64;
        if (lane == 0) *s_np = n0 + __popcll(b1);
    }
    __syncthreads();
}

// Multi-output butterfly: r[0..31] per-lane partials of 32 outputs; after the
// tree + bit5 fold, lane L holds the full sum of output (L & 31).
// 31+1 shuffles for 32 reductions (vs 6 per output).
#define BUTTERFLY32(r, lane)                                              \
    {                                                                     \
        _Pragma("unroll")                                                 \
        for (int m_ = 16; m_ >= 1; m_ >>= 1) {                            \
            _Pragma("unroll")                                             \
            for (int v_ = 0; v_ < m_; ++v_) {                             \
                float send_ = ((lane) & m_) ? r[v_] : r[v_ + m_];         \
                float got_  = __shfl_xor(send_, m_, 64);                  \
                r[v_] = (((lane) & m_) ? r[v_ + m_] : r[v_]) + got_;      \
            }                                                             \
        }                                                                 \
        r[0] += __shfl_xor(r[0], 32, 64);                                 \
    }

// ---------------------------------------------------------------------------
// Pass 1: h[p][o] = silu(x[t]·w1[e,o,:]) * (x[t]·w3[e,o,:])
// grid = (48 chunks of 16 rows, 16 experts, NZ), block = 256 (4 waves)
// Each wave owns 4 rows, as 2 half-tiles of {2 rows x 2 mats x 8 taus} = 32
// outputs resolved by one butterfly.
// ---------------------------------------------------------------------------
__global__ __launch_bounds__(256) void moe_pass1(
    const float* __restrict__ x,        // [64][1024]
    const int*   __restrict__ topk_ids, // [128]
    const float* __restrict__ w13,      // [16][1536][1024]
    float*       __restrict__ h)        // [128][768]
{
    const int e    = blockIdx.y;
    const int z    = blockIdx.z;
    const int wave = threadIdx.x >> 6;
    const int o0   = blockIdx.x * 16 + wave * 4;
    const int tid  = threadIdx.x;
    const int lane = tid & 63;

    __shared__ int   s_plist[NPAIRS];
    __shared__ int   s_np;
    __shared__ float s_x[GRP][HIDDEN];   // 32 KB

    build_plist(topk_ids, e, tid, s_plist, &s_np);
    const int np = s_np;
    if (z * GRP >= np) return;           // block-uniform: whole z-slice empty

    const float* wbase = w13 + (size_t)e * (2*INTER) * HIDDEN;

    for (int g = z; g * GRP < np; g += NZ) {
        const int gnp = min(GRP, np - g * GRP);
        for (int idx = tid; idx < gnp * (HIDDEN/4); idx += 256) {
            int tau = idx / (HIDDEN/4);
            int c   = idx % (HIDDEN/4);
            int t   = s_plist[g*GRP + tau] >> 1;
            *(float4*)(&s_x[tau][c*4]) = *(const float4*)(x + (size_t)t*HIDDEN + c*4);
        }
        __syncthreads();

        #pragma unroll
        for (int rr = 0; rr < 4; rr += 2) {
            // rm: 0 = w1 rowA, 1 = w3 rowA, 2 = w1 rowB, 3 = w3 rowB
            float4 a[4][4];
            #pragma unroll
            for (int j = 0; j < 4; ++j) {
                a[0][j] = *(const float4*)(wbase + (size_t)(o0+rr)*HIDDEN           + lane*4 + 256*j);
                a[1][j] = *(const float4*)(wbase + (size_t)(INTER + o0+rr)*HIDDEN   + lane*4 + 256*j);
                a[2][j] = *(const float4*)(wbase + (size_t)(o0+rr+1)*HIDDEN         + lane*4 + 256*j);
                a[3][j] = *(const float4*)(wbase + (size_t)(INTER + o0+rr+1)*HIDDEN + lane*4 + 256*j);
            }

            float r[32];
            #pragma unroll
            for (int v = 0; v < 32; ++v) r[v] = 0.f;

            #pragma unroll
            for (int tau = 0; tau < GRP; ++tau) {
                #pragma unroll
                for (int j = 0; j < 4; ++j) {
                    const float4 xv = *(const float4*)(&s_x[tau][lane*4 + 256*j]);
                    r[0*8 + tau] += dot4(a[0][j], xv);
                    r[1*8 + tau] += dot4(a[1][j], xv);
                    r[2*8 + tau] += dot4(a[2][j], xv);
                    r[3*8 + tau] += dot4(a[3][j], xv);
                }
            }

            BUTTERFLY32(r, lane);
            float other = __shfl_xor(r[0], 8, 64);   // pairs w1<->w3

            int idx = lane & 31;
            int tau = idx & 7;
            int rm  = idx >> 3;
            if (lane < 32 && !(rm & 1) && tau < gnp) {
                int p = s_plist[g*GRP + tau];
                float acc1 = r[0], acc3 = other;
                float gate = acc1 / (1.f + expf(-acc1));
                h[(size_t)p * INTER + (o0 + rr + (rm >> 1))] = gate * acc3;
            }
        }
        __syncthreads();
    }
}

// ---------------------------------------------------------------------------
// Pass 2: y[p][i] = sum_o h[p][o] * w2[e][i][o]
// grid = (64 chunks of 16 rows, 16 experts, NZ), block = 256
// Each wave owns 4 rows: {4 rows x 8 taus} = 32 outputs per butterfly.
// ---------------------------------------------------------------------------
__global__ __launch_bounds__(256) void moe_pass2(
    const int*   __restrict__ topk_ids, // [128]
    const float* __restrict__ w2,       // [16][1024][768]
    const float* __restrict__ h,        // [128][768]
    float*       __restrict__ y)        // [128][1024]
{
    const int e    = blockIdx.y;
    const int z    = blockIdx.z;
    const int wave = threadIdx.x >> 6;
    const int i0   = blockIdx.x * 16 + wave * 4;
    const int tid  = threadIdx.x;
    const int lane = tid & 63;

    __shared__ int   s_plist[NPAIRS];
    __shared__ int   s_np;
    __shared__ float s_h[GRP][INTER];    // 24 KB

    build_plist(topk_ids, e, tid, s_plist, &s_np);
    const int np = s_np;
    if (z * GRP >= np) return;

    // weights independent of token group: load once
    float4 a[4][3];
    #pragma unroll
    for (int j = 0; j < 3; ++j) {
        #pragma unroll
        for (int row = 0; row < 4; ++row)
            a[row][j] = *(const float4*)(w2 + ((size_t)e*HIDDEN + i0 + row)*INTER + lane*4 + 256*j);
    }

    for (int g = z; g * GRP < np; g += NZ) {
        const int gnp = min(GRP, np - g * GRP);
        for (int idx = tid; idx < gnp * (INTER/4); idx += 256) {
            int tau = idx / (INTER/4);
            int c   = idx % (INTER/4);
            int p   = s_plist[g*GRP + tau];
            *(float4*)(&s_h[tau][c*4]) = *(const float4*)(h + (size_t)p*INTER + c*4);
        }
        __syncthreads();

        float r[32];
        #pragma unroll
        for (int v = 0; v < 32; ++v) r[v] = 0.f;

        #pragma unroll
        for (int tau = 0; tau < GRP; ++tau) {
            #pragma unroll
            for (int j = 0; j < 3; ++j) {
                const float4 hv = *(const float4*)(&s_h[tau][lane*4 + 256*j]);
                r[0*8 + tau] += dot4(a[0][j], hv);
                r[1*8 + tau] += dot4(a[1][j], hv);
                r[2*8 + tau] += dot4(a[2][j], hv);
                r[3*8 + tau] += dot4(a[3][j], hv);
            }
        }

        BUTTERFLY32(r, lane);

        int idx = lane & 31;
        int tau = idx & 7;
        int row = idx >> 3;
        if (lane < 32 && tau < gnp) {
            int p = s_plist[g*GRP + tau];
            y[(size_t)p * HIDDEN + (i0 + row)] = r[0];
        }
        __syncthreads();
    }
}

// ---------------------------------------------------------------------------
// Pass 3: out[t][i] = tw[t][0]*y[2t][i] + tw[t][1]*y[2t+1][i]
// ---------------------------------------------------------------------------
__global__ __launch_bounds__(256) void moe_combine(
    const float* __restrict__ tw,   // [64][2]
    const float* __restrict__ y,    // [128][1024]
    float*       __restrict__ out)  // [64][1024]
{
    int idx = blockIdx.x * 256 + threadIdx.x;       // 16384 float4 slots
    int t = idx / (HIDDEN/4);
    int c = idx % (HIDDEN/4);
    float w0 = tw[t*2+0], w1 = tw[t*2+1];
    float4 a = *(const float4*)(y + (size_t)(2*t  )*HIDDEN + c*4);
    float4 b = *(const float4*)(y + (size_t)(2*t+1)*HIDDEN + c*4);
    float4 o;
    o.x = w0*a.x + w1*b.x;
    o.y = w0*a.y + w1*b.y;
    o.z = w0*a.z + w1*b.z;
    o.w = w0*a.w + w1*b.w;
    *(float4*)(out + (size_t)t*HIDDEN + c*4) = o;
}

extern "C" void kernel_launch(void* const* d_in, const int* in_sizes, int n_in,
                              void* d_out, int out_size, void* d_ws, size_t ws_size,
                              hipStream_t stream) {
    const float* x   = (const float*)d_in[0];
    const int*   ids = (const int*)  d_in[1];
    const float* tw  = (const float*)d_in[2];
    const float* w13 = (const float*)d_in[3];
    const float* w2  = (const float*)d_in[4];
    float* out = (float*)d_out;

    float* h = (float*)d_ws;                 // 128*768  floats
    float* y = h + (size_t)NPAIRS * INTER;   // 128*1024 floats

    dim3 g1(INTER/16, NUM_EXPERTS, NZ);    // (48, 16, 2)
    moe_pass1<<<g1, 256, 0, stream>>>(x, ids, w13, h);

    dim3 g2(HIDDEN/16, NUM_EXPERTS, NZ);   // (64, 16, 2)
    moe_pass2<<<g2, 256, 0, stream>>>(ids, w2, h, y);

    moe_combine<<<(TOKENS*HIDDEN/4)/256, 256, 0, stream>>>(tw, y, out);
}

// Round 5
// 78.897 us; speedup vs baseline: 4.8601x; 4.8601x over previous
//
#include <hip/hip_runtime.h>
#include <math.h>

#define NUM_EXPERTS 16
#define HIDDEN 1024
#define INTER 768
#define TOKENS 64
#define TOPK 2
#define NPAIRS (TOKENS*TOPK)   // 128

__device__ __forceinline__ float dot4(float4 a, float4 b) {
    return a.x*b.x + a.y*b.y + a.z*b.z + a.w*b.w;
}

// Deterministic expert pair-list build: wave 0 ballots over pairs [0,64) and
// [64,128). List is sorted by pair index -> identical across all blocks.
__device__ inline void build_plist(const int* __restrict__ topk_ids, int e,
                                   int tid, int* s_plist, int* s_np) {
    if (tid < 64) {
        const int lane = tid;
        int m0 = (topk_ids[lane]      == e);
        int m1 = (topk_ids[lane + 64] == e);
        unsigned long long b0 = __ballot(m0);
        unsigned long long b1 = __ballot(m1);
        int n0 = __popcll(b0);
        unsigned long long below = (lane == 0) ? 0ull : ((1ull << lane) - 1ull);
        if (m0) s_plist[__popcll(b0 & below)]      = lane;
        if (m1) s_plist[n0 + __popcll(b1 & below)] = lane + 64;
        if (lane == 0) *s_np = n0 + __popcll(b1);
    }
    __syncthreads();
}

// ---------------------------------------------------------------------------
// Pass 1: h[p][o] = silu(x[t]·w1[e,o,:]) * (x[t]·w3[e,o,:])
// grid = (INTER/8 = 96, 16 experts), block = 256 (4 waves).
// Each wave owns 2 output rows. Lane groups of 16:
//   g0: w1·rowA   g1: w3·rowA   g2: w1·rowB   g3: w3·rowB
// Each lane holds a 64-float K-slice of its row in 16 float4 regs (reused
// across all tokens). Reduction = 4 shuffles within the 16-lane group + 1
// pairing shuffle (w1<->w3) = 5 shuffles / 2 outputs.
// ---------------------------------------------------------------------------
__global__ __launch_bounds__(256) void moe_pass1(
    const float* __restrict__ x,        // [64][1024]
    const int*   __restrict__ topk_ids, // [128]
    const float* __restrict__ w13,      // [16][1536][1024]
    float*       __restrict__ h)        // [128][768]
{
    const int e    = blockIdx.y;
    const int tid  = threadIdx.x;
    const int wave = tid >> 6;
    const int lane = tid & 63;
    const int g    = lane >> 4;
    const int l16  = lane & 15;

    const int row  = blockIdx.x * 8 + wave * 2 + (g >> 1);
    const int mat  = g & 1;

    __shared__ int s_plist[NPAIRS];
    __shared__ int s_np;
    build_plist(topk_ids, e, tid, s_plist, &s_np);
    const int np = s_np;
    if (np == 0) return;

    const float* wrow = w13 + ((size_t)e * (2*INTER) + (size_t)mat * INTER + row) * HIDDEN + l16 * 4;
    float4 w[16];
    #pragma unroll
    for (int j = 0; j < 16; ++j)
        w[j] = *(const float4*)(wrow + j * 64);

    for (int s = 0; s < np; ++s) {
        const int p = s_plist[s];
        const float* xrow = x + (size_t)(p >> 1) * HIDDEN + l16 * 4;
        float a0 = 0.f, a1 = 0.f, a2 = 0.f, a3 = 0.f;
        #pragma unroll
        for (int j = 0; j < 16; j += 4) {
            a0 += dot4(w[j+0], *(const float4*)(xrow + (j+0) * 64));
            a1 += dot4(w[j+1], *(const float4*)(xrow + (j+1) * 64));
            a2 += dot4(w[j+2], *(const float4*)(xrow + (j+2) * 64));
            a3 += dot4(w[j+3], *(const float4*)(xrow + (j+3) * 64));
        }
        float acc = (a0 + a1) + (a2 + a3);
        acc += __shfl_xor(acc, 1, 64);
        acc += __shfl_xor(acc, 2, 64);
        acc += __shfl_xor(acc, 4, 64);
        acc += __shfl_xor(acc, 8, 64);
        float other = __shfl_xor(acc, 16, 64);   // pairs w1 <-> w3
        if (mat == 0 && l16 == 0) {
            float gate = acc / (1.f + expf(-acc));
            h[(size_t)p * INTER + row] = gate * other;
        }
    }
}

// ---------------------------------------------------------------------------
// Pass 2: y[p][i] = sum_o h[p][o] * w2[e][i][o]
// grid = (HIDDEN/16 = 64, 16 experts), block = 256 (4 waves).
// Each wave owns 4 rows (one per 16-lane group); lane holds a 48-float
// K-slice (12 float4). 4 shuffles per reduce, 4 outputs per token per wave.
// ---------------------------------------------------------------------------
__global__ __launch_bounds__(256) void moe_pass2(
    const int*   __restrict__ topk_ids, // [128]
    const float* __restrict__ w2,       // [16][1024][768]
    const float* __restrict__ h,        // [128][768]
    float*       __restrict__ y)        // [128][1024]
{
    const int e    = blockIdx.y;
    const int tid  = threadIdx.x;
    const int wave = tid >> 6;
    const int lane = tid & 63;
    const int g    = lane >> 4;
    const int l16  = lane & 15;

    const int row  = blockIdx.x * 16 + wave * 4 + g;

    __shared__ int s_plist[NPAIRS];
    __shared__ int s_np;
    build_plist(topk_ids, e, tid, s_plist, &s_np);
    const int np = s_np;
    if (np == 0) return;

    const float* wrow = w2 + ((size_t)e * HIDDEN + row) * INTER + l16 * 4;
    float4 w[12];
    #pragma unroll
    for (int j = 0; j < 12; ++j)
        w[j] = *(const float4*)(wrow + j * 64);

    for (int s = 0; s < np; ++s) {
        const int p = s_plist[s];
        const float* hrow = h + (size_t)p * INTER + l16 * 4;
        float a0 = 0.f, a1 = 0.f, a2 = 0.f, a3 = 0.f;
        #pragma unroll
        for (int j = 0; j < 12; j += 4) {
            a0 += dot4(w[j+0], *(const float4*)(hrow + (j+0) * 64));
            a1 += dot4(w[j+1], *(const float4*)(hrow + (j+1) * 64));
            a2 += dot4(w[j+2], *(const float4*)(hrow + (j+2) * 64));
            a3 += dot4(w[j+3], *(const float4*)(hrow + (j+3) * 64));
        }
        float acc = (a0 + a1) + (a2 + a3);
        acc += __shfl_xor(acc, 1, 64);
        acc += __shfl_xor(acc, 2, 64);
        acc += __shfl_xor(acc, 4, 64);
        acc += __shfl_xor(acc, 8, 64);
        if (l16 == 0) {
            y[(size_t)p * HIDDEN + row] = acc;
        }
    }
}

// ---------------------------------------------------------------------------
// Pass 3: out[t][i] = tw[t][0]*y[2t][i] + tw[t][1]*y[2t+1][i]
// ---------------------------------------------------------------------------
__global__ __launch_bounds__(256) void moe_combine(
    const float* __restrict__ tw,   // [64][2]
    const float* __restrict__ y,    // [128][1024]
    float*       __restrict__ out)  // [64][1024]
{
    int idx = blockIdx.x * 256 + threadIdx.x;       // 16384 float4 slots
    int t = idx / (HIDDEN/4);
    int c = idx % (HIDDEN/4);
    float w0 = tw[t*2+0], w1 = tw[t*2+1];
    float4 a = *(const float4*)(y + (size_t)(2*t  )*HIDDEN + c*4);
    float4 b = *(const float4*)(y + (size_t)(2*t+1)*HIDDEN + c*4);
    float4 o;
    o.x = w0*a.x + w1*b.x;
    o.y = w0*a.y + w1*b.y;
    o.z = w0*a.z + w1*b.z;
    o.w = w0*a.w + w1*b.w;
    *(float4*)(out + (size_t)t*HIDDEN + c*4) = o;
}

extern "C" void kernel_launch(void* const* d_in, const int* in_sizes, int n_in,
                              void* d_out, int out_size, void* d_ws, size_t ws_size,
                              hipStream_t stream) {
    const float* x   = (const float*)d_in[0];
    const int*   ids = (const int*)  d_in[1];
    const float* tw  = (const float*)d_in[2];
    const float* w13 = (const float*)d_in[3];
    const float* w2  = (const float*)d_in[4];
    float* out = (float*)d_out;

    float* h = (float*)d_ws;                 // 128*768  floats
    float* y = h + (size_t)NPAIRS * INTER;   // 128*1024 floats

    dim3 g1(INTER/8, NUM_EXPERTS);     // (96, 16)
    moe_pass1<<<g1, 256, 0, stream>>>(x, ids, w13, h);

    dim3 g2(HIDDEN/16, NUM_EXPERTS);   // (64, 16)
    moe_pass2<<<g2, 256, 0, stream>>>(ids, w2, h, y);

    moe_combine<<<(TOKENS*HIDDEN/4)/256, 256, 0, stream>>>(tw, y, out);
}

// Round 6
// 71.219 us; speedup vs baseline: 5.3840x; 1.1078x over previous
//
#include <hip/hip_runtime.h>
#include <math.h>

#define NUM_EXPERTS 16
#define HIDDEN 1024
#define INTER 768
#define TOKENS 64
#define TOPK 2
#define NPAIRS (TOKENS*TOPK)   // 128

__device__ __forceinline__ float dot4(float4 a, float4 b) {
    return a.x*b.x + a.y*b.y + a.z*b.z + a.w*b.w;
}

// Deterministic expert pair-list build: wave 0 ballots over pairs [0,64) and
// [64,128). List is sorted by pair index -> identical across all blocks.
__device__ inline void build_plist(const int* __restrict__ topk_ids, int e,
                                   int tid, int* s_plist, int* s_np) {
    if (tid < 64) {
        const int lane = tid;
        int m0 = (topk_ids[lane]      == e);
        int m1 = (topk_ids[lane + 64] == e);
        unsigned long long b0 = __ballot(m0);
        unsigned long long b1 = __ballot(m1);
        int n0 = __popcll(b0);
        unsigned long long below = (lane == 0) ? 0ull : ((1ull << lane) - 1ull);
        if (m0) s_plist[__popcll(b0 & below)]      = lane;
        if (m1) s_plist[n0 + __popcll(b1 & below)] = lane + 64;
        if (lane == 0) *s_np = n0 + __popcll(b1);
    }
    __syncthreads();
}

// ---------------------------------------------------------------------------
// Pass 1: h[p][o] = silu(x[t]·w1[e,o,:]) * (x[t]·w3[e,o,:])
// grid = (INTER/4 = 192, 16 experts), block = 256 (4 waves, 1 row per wave).
// Wave halves: lanes 0-31 = w1·row, lanes 32-63 = w3·row. Each lane holds an
// 8-float4 (32-reg) K-slice — small enough that the allocator keeps it
// resident (pass2 with 12 float4 stayed resident at VGPR=52; 16 did not).
// Reduce: 5 shfl_xor within the 32-half + 1 pairing shfl_xor(·,32).
// ---------------------------------------------------------------------------
__global__ __launch_bounds__(256) void moe_pass1(
    const float* __restrict__ x,        // [64][1024]
    const int*   __restrict__ topk_ids, // [128]
    const float* __restrict__ w13,      // [16][1536][1024]
    float*       __restrict__ h)        // [128][768]
{
    const int e    = blockIdx.y;
    const int tid  = threadIdx.x;
    const int wave = tid >> 6;
    const int lane = tid & 63;
    const int mat  = lane >> 5;          // 0 = w1, 1 = w3
    const int l32  = lane & 31;

    const int row  = blockIdx.x * 4 + wave;

    __shared__ int s_plist[NPAIRS];
    __shared__ int s_np;
    build_plist(topk_ids, e, tid, s_plist, &s_np);
    const int np = s_np;
    if (np == 0) return;

    const float* wrow = w13 + ((size_t)e * (2*INTER) + (size_t)mat * INTER + row) * HIDDEN + l32 * 4;
    float4 w[8];
    #pragma unroll
    for (int j = 0; j < 8; ++j)
        w[j] = *(const float4*)(wrow + j * 128);

    for (int s = 0; s < np; ++s) {
        const int p = s_plist[s];
        const float* xrow = x + (size_t)(p >> 1) * HIDDEN + l32 * 4;
        float a0 = 0.f, a1 = 0.f, a2 = 0.f, a3 = 0.f;
        #pragma unroll
        for (int j = 0; j < 8; j += 4) {
            a0 += dot4(w[j+0], *(const float4*)(xrow + (j+0) * 128));
            a1 += dot4(w[j+1], *(const float4*)(xrow + (j+1) * 128));
            a2 += dot4(w[j+2], *(const float4*)(xrow + (j+2) * 128));
            a3 += dot4(w[j+3], *(const float4*)(xrow + (j+3) * 128));
        }
        float acc = (a0 + a1) + (a2 + a3);
        acc += __shfl_xor(acc, 1, 64);
        acc += __shfl_xor(acc, 2, 64);
        acc += __shfl_xor(acc, 4, 64);
        acc += __shfl_xor(acc, 8, 64);
        acc += __shfl_xor(acc, 16, 64);
        float other = __shfl_xor(acc, 32, 64);   // pairs w1 <-> w3
        if (lane == 0) {
            float gate = acc / (1.f + expf(-acc));
            h[(size_t)p * INTER + row] = gate * other;
        }
    }
}

// ---------------------------------------------------------------------------
// Pass 2: y[p][i] = sum_o h[p][o] * w2[e][i][o]
// grid = (HIDDEN/16 = 64, 16 experts), block = 256 (4 waves).
// Each wave owns 4 rows (one per 16-lane group); lane holds a 48-float
// K-slice (12 float4). 4 shuffles per reduce, 4 outputs per token per wave.
// ---------------------------------------------------------------------------
__global__ __launch_bounds__(256) void moe_pass2(
    const int*   __restrict__ topk_ids, // [128]
    const float* __restrict__ w2,       // [16][1024][768]
    const float* __restrict__ h,        // [128][768]
    float*       __restrict__ y)        // [128][1024]
{
    const int e    = blockIdx.y;
    const int tid  = threadIdx.x;
    const int wave = tid >> 6;
    const int lane = tid & 63;
    const int g    = lane >> 4;
    const int l16  = lane & 15;

    const int row  = blockIdx.x * 16 + wave * 4 + g;

    __shared__ int s_plist[NPAIRS];
    __shared__ int s_np;
    build_plist(topk_ids, e, tid, s_plist, &s_np);
    const int np = s_np;
    if (np == 0) return;

    const float* wrow = w2 + ((size_t)e * HIDDEN + row) * INTER + l16 * 4;
    float4 w[12];
    #pragma unroll
    for (int j = 0; j < 12; ++j)
        w[j] = *(const float4*)(wrow + j * 64);

    for (int s = 0; s < np; ++s) {
        const int p = s_plist[s];
        const float* hrow = h + (size_t)p * INTER + l16 * 4;
        float a0 = 0.f, a1 = 0.f, a2 = 0.f, a3 = 0.f;
        #pragma unroll
        for (int j = 0; j < 12; j += 4) {
            a0 += dot4(w[j+0], *(const float4*)(hrow + (j+0) * 64));
            a1 += dot4(w[j+1], *(const float4*)(hrow + (j+1) * 64));
            a2 += dot4(w[j+2], *(const float4*)(hrow + (j+2) * 64));
            a3 += dot4(w[j+3], *(const float4*)(hrow + (j+3) * 64));
        }
        float acc = (a0 + a1) + (a2 + a3);
        acc += __shfl_xor(acc, 1, 64);
        acc += __shfl_xor(acc, 2, 64);
        acc += __shfl_xor(acc, 4, 64);
        acc += __shfl_xor(acc, 8, 64);
        if (l16 == 0) {
            y[(size_t)p * HIDDEN + row] = acc;
        }
    }
}

// ---------------------------------------------------------------------------
// Pass 3: out[t][i] = tw[t][0]*y[2t][i] + tw[t][1]*y[2t+1][i]
// ---------------------------------------------------------------------------
__global__ __launch_bounds__(256) void moe_combine(
    const float* __restrict__ tw,   // [64][2]
    const float* __restrict__ y,    // [128][1024]
    float*       __restrict__ out)  // [64][1024]
{
    int idx = blockIdx.x * 256 + threadIdx.x;       // 16384 float4 slots
    int t = idx / (HIDDEN/4);
    int c = idx % (HIDDEN/4);
    float w0 = tw[t*2+0], w1 = tw[t*2+1];
    float4 a = *(const float4*)(y + (size_t)(2*t  )*HIDDEN + c*4);
    float4 b = *(const float4*)(y + (size_t)(2*t+1)*HIDDEN + c*4);
    float4 o;
    o.x = w0*a.x + w1*b.x;
    o.y = w0*a.y + w1*b.y;
    o.z = w0*a.z + w1*b.z;
    o.w = w0*a.w + w1*b.w;
    *(float4*)(out + (size_t)t*HIDDEN + c*4) = o;
}

extern "C" void kernel_launch(void* const* d_in, const int* in_sizes, int n_in,
                              void* d_out, int out_size, void* d_ws, size_t ws_size,
                              hipStream_t stream) {
    const float* x   = (const float*)d_in[0];
    const int*   ids = (const int*)  d_in[1];
    const float* tw  = (const float*)d_in[2];
    const float* w13 = (const float*)d_in[3];
    const float* w2  = (const float*)d_in[4];
    float* out = (float*)d_out;

    float* h = (float*)d_ws;                 // 128*768  floats
    float* y = h + (size_t)NPAIRS * INTER;   // 128*1024 floats

    dim3 g1(INTER/4, NUM_EXPERTS);     // (192, 16)
    moe_pass1<<<g1, 256, 0, stream>>>(x, ids, w13, h);

    dim3 g2(HIDDEN/16, NUM_EXPERTS);   // (64, 16)
    moe_pass2<<<g2, 256, 0, stream>>>(ids, w2, h, y);

    moe_combine<<<(TOKENS*HIDDEN/4)/256, 256, 0, stream>>>(tw, y, out);
}